// Round 1
// baseline (1381.434 us; speedup 1.0000x reference)
//
#include <hip/hip_runtime.h>
#include <hip/hip_bf16.h>
#include <cstdint>

#define B_   2
#define S_   2048
#define D_   1024
#define H_   16
#define DPH_ 64

// ---------------- mask format detection ----------------
// Scan first 2,097,152 words (== full uint8 mask size; <= 1/4 of int32/float32 size).
// flags[0]: any word > 1            -> not int32{0,1}
// flags[1]: any word not in {0,1.0f} -> not float32
__global__ __launch_bounds__(256) void detect_mask_fmt(const unsigned int* __restrict__ m,
                                                       unsigned int* __restrict__ flags) {
  int i = blockIdx.x * 256 + threadIdx.x;
  unsigned a = 0, b = 0;
#pragma unroll
  for (int p = 0; p < 4; ++p) {
    unsigned v = m[(size_t)i * 4 + p];
    if (v > 1u) a = 1u;
    if (v != 0u && v != 0x3f800000u) b = 1u;
  }
  if (a) atomicOr(&flags[0], 1u);
  if (b) atomicOr(&flags[1], 1u);
}

// Normalize mask to uint8 (1 = disallowed). 2,097,152 threads x 4 elements.
__global__ __launch_bounds__(256) void prep_mask(const void* __restrict__ src,
                                                 const unsigned int* __restrict__ flags,
                                                 uchar4* __restrict__ dst) {
  int i = blockIdx.x * 256 + threadIdx.x;
  unsigned fa = flags[0], fb = flags[1];
  uchar4 r;
  if (fa == 0u || fb == 0u) {            // 4-byte elements (int32 or float32)
    int4 w = ((const int4*)src)[i];
    r.x = (unsigned char)(w.x != 0); r.y = (unsigned char)(w.y != 0);
    r.z = (unsigned char)(w.z != 0); r.w = (unsigned char)(w.w != 0);
  } else {                               // 1-byte elements (bool/uint8)
    uchar4 u = ((const uchar4*)src)[i];
    r.x = (unsigned char)(u.x != 0); r.y = (unsigned char)(u.y != 0);
    r.z = (unsigned char)(u.z != 0); r.w = (unsigned char)(u.w != 0);
  }
  dst[i] = r;
}

// ---------------- fp32 GEMM: C[m,n] = scale*(sum_k A[m,k]*W[k,n] + bias[n]) ----------------
// A: [M,1024] row-major, W: [1024,1024] row-major. Tile 128x128x16, 256 thr, 8x8 microtile.
__global__ __launch_bounds__(256) void gemm_f32(const float* __restrict__ A,
                                                const float* __restrict__ W,
                                                const float* __restrict__ bias,
                                                float* __restrict__ C,
                                                float scale) {
  __shared__ float As[16][132];   // As[k][m]  (transposed on store)
  __shared__ float Ws[16][132];   // Ws[k][n]
  const int tid = threadIdx.x;
  const int m0 = blockIdx.y * 128;
  const int n0 = blockIdx.x * 128;
  const int ty = tid >> 4, tx = tid & 15;
  float acc[8][8] = {};
  for (int k0 = 0; k0 < D_; k0 += 16) {
#pragma unroll
    for (int p = 0; p < 2; ++p) {
      int idx = tid + p * 256;
      int ar = idx >> 2, ac = (idx & 3) << 2;
      float4 av = *(const float4*)(A + (size_t)(m0 + ar) * D_ + k0 + ac);
      As[ac + 0][ar] = av.x; As[ac + 1][ar] = av.y;
      As[ac + 2][ar] = av.z; As[ac + 3][ar] = av.w;
      int wr = idx >> 5, wc = (idx & 31) << 2;
      *(float4*)&Ws[wr][wc] = *(const float4*)(W + (size_t)(k0 + wr) * D_ + n0 + wc);
    }
    __syncthreads();
#pragma unroll
    for (int k = 0; k < 16; ++k) {
      float a[8], b[8];
      *(float4*)&a[0] = *(const float4*)&As[k][ty * 8];
      *(float4*)&a[4] = *(const float4*)&As[k][ty * 8 + 4];
      *(float4*)&b[0] = *(const float4*)&Ws[k][tx * 8];
      *(float4*)&b[4] = *(const float4*)&Ws[k][tx * 8 + 4];
#pragma unroll
      for (int i = 0; i < 8; ++i)
#pragma unroll
        for (int j = 0; j < 8; ++j)
          acc[i][j] = fmaf(a[i], b[j], acc[i][j]);
    }
    __syncthreads();
  }
#pragma unroll
  for (int i = 0; i < 8; ++i) {
    int gm = m0 + ty * 8 + i;
#pragma unroll
    for (int j = 0; j < 8; j += 4) {
      int gn = n0 + tx * 8 + j;
      float4 o;
      o.x = scale * (acc[i][j + 0] + bias[gn + 0]);
      o.y = scale * (acc[i][j + 1] + bias[gn + 1]);
      o.z = scale * (acc[i][j + 2] + bias[gn + 2]);
      o.w = scale * (acc[i][j + 3] + bias[gn + 3]);
      *(float4*)(C + (size_t)gm * D_ + gn) = o;
    }
  }
}

// ---------------- flash attention (fp32), 64 q-rows x 64 k-cols per iter ----------------
// Q pre-scaled by 1/sqrt(DPH). CTX may alias Q (block reads exactly the region it writes,
// all reads complete into LDS before the epilogue write; regions disjoint across blocks).
__global__ __launch_bounds__(256) void attn_f32(const float* __restrict__ Q,
                                                const float* __restrict__ K,
                                                const float* __restrict__ V,
                                                const unsigned char* __restrict__ M8,
                                                float* __restrict__ CTX) {
  __shared__ float qs[64][68];    // qs[d][r]   (Q^T)
  __shared__ float kps[64][68];   // K^T [d][c], reused as P^T [c][r]
  __shared__ float vs[64][68];    // vs[k][d]
  const int tid = threadIdx.x;
  const int bh = blockIdx.y;
  const int b = bh >> 4, h = bh & (H_ - 1);
  const int q0 = blockIdx.x * 64;
  const size_t base = ((size_t)b * S_) * D_ + (size_t)h * DPH_;

#pragma unroll
  for (int p = 0; p < 4; ++p) {
    int idx = tid + p * 256;
    int r = idx >> 4, d4 = (idx & 15) << 2;
    float4 v = *(const float4*)(Q + base + (size_t)(q0 + r) * D_ + d4);
    qs[d4 + 0][r] = v.x; qs[d4 + 1][r] = v.y;
    qs[d4 + 2][r] = v.z; qs[d4 + 3][r] = v.w;
  }
  const int ty = tid >> 4, tx = tid & 15;
  float mr[4] = {-3e38f, -3e38f, -3e38f, -3e38f};
  float l[4]  = {0.f, 0.f, 0.f, 0.f};
  float acc[4][4] = {};
  const size_t mbase = (size_t)b * S_ * S_;

  for (int kt = 0; kt < S_ / 64; ++kt) {
    const int k0 = kt * 64;
#pragma unroll
    for (int p = 0; p < 4; ++p) {
      int idx = tid + p * 256;
      int r = idx >> 4, d4 = (idx & 15) << 2;
      float4 kv = *(const float4*)(K + base + (size_t)(k0 + r) * D_ + d4);
      kps[d4 + 0][r] = kv.x; kps[d4 + 1][r] = kv.y;
      kps[d4 + 2][r] = kv.z; kps[d4 + 3][r] = kv.w;
      *(float4*)&vs[r][d4] = *(const float4*)(V + base + (size_t)(k0 + r) * D_ + d4);
    }
    __syncthreads();

    // scores: S = Q_tile (64x64) . K_tile^T  -> 4x4 per thread
    float s[4][4] = {};
#pragma unroll 8
    for (int d = 0; d < 64; ++d) {
      float4 a  = *(const float4*)&qs[d][ty * 4];
      float4 kk = *(const float4*)&kps[d][tx * 4];
      float av[4] = {a.x, a.y, a.z, a.w};
      float bv[4] = {kk.x, kk.y, kk.z, kk.w};
#pragma unroll
      for (int i = 0; i < 4; ++i)
#pragma unroll
        for (int j = 0; j < 4; ++j)
          s[i][j] = fmaf(av[i], bv[j], s[i][j]);
    }

    // mask + online softmax (row stats across the 16 lanes sharing ty)
    float pv[4][4];
#pragma unroll
    for (int i = 0; i < 4; ++i) {
      unsigned mw = *(const unsigned int*)(M8 + mbase + (size_t)(q0 + ty * 4 + i) * S_ + k0 + tx * 4);
      float se[4];
#pragma unroll
      for (int j = 0; j < 4; ++j) {
        bool dis = ((mw >> (8 * j)) & 0xffu) != 0u;
        se[j] = dis ? -3e38f : s[i][j];
      }
      float tm = fmaxf(fmaxf(se[0], se[1]), fmaxf(se[2], se[3]));
#pragma unroll
      for (int o = 1; o < 16; o <<= 1) tm = fmaxf(tm, __shfl_xor(tm, o, 16));
      float mnew = fmaxf(mr[i], tm);
      float f = __expf(mr[i] - mnew);
      float rs = 0.f;
#pragma unroll
      for (int j = 0; j < 4; ++j) {
        float pj = (se[j] < -1e38f) ? 0.f : __expf(se[j] - mnew);
        pv[i][j] = pj; rs += pj;
      }
#pragma unroll
      for (int o = 1; o < 16; o <<= 1) rs += __shfl_xor(rs, o, 16);
      l[i] = l[i] * f + rs;
      mr[i] = mnew;
      acc[i][0] *= f; acc[i][1] *= f; acc[i][2] *= f; acc[i][3] *= f;
    }
    __syncthreads();          // everyone done reading kps as K
#pragma unroll
    for (int i = 0; i < 4; ++i)
#pragma unroll
      for (int j = 0; j < 4; ++j)
        kps[tx * 4 + j][ty * 4 + i] = pv[i][j];   // P^T
    __syncthreads();

    // PV: acc += P_tile (64x64) . V_tile (64x64)
#pragma unroll 8
    for (int k = 0; k < 64; ++k) {
      float4 a  = *(const float4*)&kps[k][ty * 4];
      float4 vv = *(const float4*)&vs[k][tx * 4];
      float av[4] = {a.x, a.y, a.z, a.w};
      float bv[4] = {vv.x, vv.y, vv.z, vv.w};
#pragma unroll
      for (int i = 0; i < 4; ++i)
#pragma unroll
        for (int j = 0; j < 4; ++j)
          acc[i][j] = fmaf(av[i], bv[j], acc[i][j]);
    }
    __syncthreads();
  }

#pragma unroll
  for (int i = 0; i < 4; ++i) {
    float inv = 1.f / l[i];
    float4 o = make_float4(acc[i][0] * inv, acc[i][1] * inv, acc[i][2] * inv, acc[i][3] * inv);
    *(float4*)(CTX + base + (size_t)(q0 + ty * 4 + i) * D_ + tx * 4) = o;
  }
}

// ---------------- launch ----------------
extern "C" void kernel_launch(void* const* d_in, const int* in_sizes, int n_in,
                              void* d_out, int out_size, void* d_ws, size_t ws_size,
                              hipStream_t stream) {
  const float* key   = (const float*)d_in[0];
  const float* value = (const float*)d_in[1];
  const float* query = (const float*)d_in[2];
  const void*  mask  = d_in[3];
  const float* Wq = (const float*)d_in[4];
  const float* bq = (const float*)d_in[5];
  const float* Wk = (const float*)d_in[6];
  const float* bk = (const float*)d_in[7];
  const float* Wv = (const float*)d_in[8];
  const float* bv = (const float*)d_in[9];
  const float* Wo = (const float*)d_in[10];
  const float* bo = (const float*)d_in[11];
  float* out = (float*)d_out;

  const size_t NE = (size_t)B_ * S_ * D_;            // 4,194,304 floats each
  float* Qb = (float*)d_ws;                          // also CTX (safe alias, see attn_f32)
  float* Kb = Qb + NE;
  float* Vb = Kb + NE;
  unsigned char* m8 = (unsigned char*)(Vb + NE);     // B*S*S bytes
  unsigned int* flags = (unsigned int*)(m8 + (size_t)B_ * S_ * S_);

  hipMemsetAsync(flags, 0, 8, stream);
  detect_mask_fmt<<<2048, 256, 0, stream>>>((const unsigned int*)mask, flags);
  prep_mask<<<8192, 256, 0, stream>>>(mask, flags, (uchar4*)m8);

  dim3 ggrid(D_ / 128, (B_ * S_) / 128);             // (8, 32)
  gemm_f32<<<ggrid, 256, 0, stream>>>(query, Wq, bq, Qb, 0.125f);  // q/sqrt(DPH)
  gemm_f32<<<ggrid, 256, 0, stream>>>(key,   Wk, bk, Kb, 1.0f);
  gemm_f32<<<ggrid, 256, 0, stream>>>(value, Wv, bv, Vb, 1.0f);

  attn_f32<<<dim3(S_ / 64, B_ * H_), 256, 0, stream>>>(Qb, Kb, Vb, m8, Qb);

  gemm_f32<<<ggrid, 256, 0, stream>>>(Qb, Wo, bo, out, 1.0f);
}

// Round 2
// 491.746 us; speedup vs baseline: 2.8092x; 2.8092x over previous
//
#include <hip/hip_runtime.h>
#include <hip/hip_bf16.h>
#include <cstdint>

#define B_   2
#define S_   2048
#define D_   1024
#define H_   16
#define DPH_ 64

typedef float f32x4 __attribute__((ext_vector_type(4)));
typedef short bf16x8 __attribute__((ext_vector_type(8)));
typedef unsigned short u16;

static const size_t NE = (size_t)B_ * S_ * D_;   // 4,194,304 elements

__device__ __forceinline__ u16 f2bf(float f) {
  union { float f; unsigned u; } cv; cv.f = f;
  unsigned u = cv.u;
  return (u16)((u + 0x7fffu + ((u >> 16) & 1u)) >> 16);
}

__device__ __forceinline__ void gld16(const void* g, void* l) {
  __builtin_amdgcn_global_load_lds((const __attribute__((address_space(1))) unsigned int*)g,
                                   (__attribute__((address_space(3))) unsigned int*)l, 16, 0, 0);
}

// ---------------- mask format detection (scans first 8MB as u32 words) ----------------
__global__ __launch_bounds__(256) void detect_mask_fmt(const unsigned int* __restrict__ m,
                                                       unsigned int* __restrict__ flags) {
  int i = blockIdx.x * 256 + threadIdx.x;
  unsigned a = 0, b = 0;
#pragma unroll
  for (int p = 0; p < 4; ++p) {
    unsigned v = m[(size_t)i * 4 + p];
    if (v > 1u) a = 1u;
    if (v != 0u && v != 0x3f800000u) b = 1u;
  }
  if (a) atomicOr(&flags[0], 1u);
  if (b) atomicOr(&flags[1], 1u);
}

// ---------------- mask -> bitmask: M1[b][q][w] u64, bit k = disallowed ----------------
__device__ __forceinline__ unsigned nz4(unsigned w) {
  unsigned r = 0;
  if (w & 0x000000ffu) r |= 1u;
  if (w & 0x0000ff00u) r |= 2u;
  if (w & 0x00ff0000u) r |= 4u;
  if (w & 0xff000000u) r |= 8u;
  return r;
}

__global__ __launch_bounds__(256) void prep_bits(const void* __restrict__ src,
                                                 const unsigned int* __restrict__ flags,
                                                 unsigned long long* __restrict__ dst) {
  int i = blockIdx.x * 256 + threadIdx.x;          // 131072 words
  unsigned long long w = 0;
  bool fourB = (flags[0] == 0u) || (flags[1] == 0u);
  if (fourB) {
    const uint4* p = (const uint4*)src + (size_t)i * 16;
#pragma unroll
    for (int j = 0; j < 16; ++j) {
      uint4 v = p[j];
      unsigned bits = (v.x ? 1u : 0u) | (v.y ? 2u : 0u) | (v.z ? 4u : 0u) | (v.w ? 8u : 0u);
      w |= (unsigned long long)bits << (j * 4);
    }
  } else {
    const uint4* p = (const uint4*)src + (size_t)i * 4;
#pragma unroll
    for (int j = 0; j < 4; ++j) {
      uint4 v = p[j];
      w |= (unsigned long long)nz4(v.x) << (j * 16 + 0);
      w |= (unsigned long long)nz4(v.y) << (j * 16 + 4);
      w |= (unsigned long long)nz4(v.z) << (j * 16 + 8);
      w |= (unsigned long long)nz4(v.w) << (j * 16 + 12);
    }
  }
  dst[i] = w;
}

// ---------------- f32 -> bf16 conversion (8 elems/thread) ----------------
__global__ __launch_bounds__(256) void cvt_in(const float4* __restrict__ src,
                                              bf16x8* __restrict__ dst) {
  int i = blockIdx.x * 256 + threadIdx.x;
  float4 a = src[(size_t)i * 2], c = src[(size_t)i * 2 + 1];
  bf16x8 v;
  v[0] = (short)f2bf(a.x); v[1] = (short)f2bf(a.y);
  v[2] = (short)f2bf(a.z); v[3] = (short)f2bf(a.w);
  v[4] = (short)f2bf(c.x); v[5] = (short)f2bf(c.y);
  v[6] = (short)f2bf(c.z); v[7] = (short)f2bf(c.w);
  dst[i] = v;
}

// ---------------- weight transpose + convert: WT[n][k] = bf16(W[k][n]) ----------------
__global__ __launch_bounds__(256) void cvt_wT(const float* __restrict__ Wq, const float* __restrict__ Wk,
                                              const float* __restrict__ Wv, const float* __restrict__ Wo,
                                              u16* __restrict__ WT) {
  const float* W = (blockIdx.y == 0) ? Wq : (blockIdx.y == 1) ? Wk : (blockIdx.y == 2) ? Wv : Wo;
  u16* O = WT + (size_t)blockIdx.y * D_ * D_;
  int t = blockIdx.x * 256 + threadIdx.x;          // 131072 threads
  int n = t & 1023, k8 = (t >> 10) << 3;
  bf16x8 v;
#pragma unroll
  for (int j = 0; j < 8; ++j) v[j] = (short)f2bf(W[(size_t)(k8 + j) * D_ + n]);
  *(bf16x8*)(O + (size_t)n * D_ + k8) = v;
}

// ---------------- bf16 MFMA GEMM: C = scale*(A @ WT^T + bias) ----------------
// A [M][1024] bf16 row-major, WT [1024 n][1024 k] bf16 (pre-transposed weights).
// 128x128 tile, BK=32, 4 waves (2x2 of 64x64), dbuf LDS, counted vmcnt.
// OUTMODE: 0 = bf16 [M][1024]; 1 = f32 [M][1024]; 2 = bf16 VT[b][h][dn][s] (per-head transpose)
template <int OUTMODE>
__global__ __launch_bounds__(256, 2) void gemm_bf16(const u16* __restrict__ A,
                                                    const u16* __restrict__ WT,
                                                    const float* __restrict__ bias,
                                                    void* __restrict__ Cout, float scale) {
  __shared__ unsigned char sA[2][8192];
  __shared__ unsigned char sB[2][8192];
  const int tid = threadIdx.x, wv = tid >> 6, lane = tid & 63;
  const int hi = lane >> 4, lo = lane & 15;
  const int wm = wv >> 1, wn = wv & 1;
  const int m0 = blockIdx.y * 128, n0 = blockIdx.x * 128;
  const char* ag = (const char*)A + (size_t)m0 * 2048;
  const char* bg = (const char*)WT + (size_t)n0 * 2048;

  f32x4 acc[4][4];
#pragma unroll
  for (int i = 0; i < 4; ++i)
#pragma unroll
    for (int j = 0; j < 4; ++j) acc[i][j] = (f32x4){0.f, 0.f, 0.f, 0.f};

  // stage one 8KB tile (128 rows x 64B), rows stride 2048B, 4 chunks/row, XOR-swizzled source
  auto stageg = [&](unsigned char* dst, const char* srcbase, int koff) {
#pragma unroll
    for (int p = 0; p < 2; ++p) {
      int cid = p * 4 + wv;
      int slot = cid * 64 + lane;
      int r = slot >> 2, c = slot & 3;
      gld16(srcbase + (size_t)r * 2048 + koff + ((c ^ (r & 3)) * 16), dst + cid * 1024);
    }
  };

  stageg(sA[0], ag, 0);
  stageg(sB[0], bg, 0);

  for (int kt = 0; kt < 32; ++kt) {
    int cur = kt & 1;
    if (kt < 31) {
      stageg(sA[cur ^ 1], ag, (kt + 1) * 64);
      stageg(sB[cur ^ 1], bg, (kt + 1) * 64);
      asm volatile("s_waitcnt vmcnt(4)" ::: "memory");
    } else {
      asm volatile("s_waitcnt vmcnt(0)" ::: "memory");
    }
    __builtin_amdgcn_s_barrier();
    __builtin_amdgcn_sched_barrier(0);

    bf16x8 af[4], bf[4];
#pragma unroll
    for (int i = 0; i < 4; ++i) {
      int mr = 64 * wm + 16 * i + lo;
      af[i] = *(const bf16x8*)(sA[cur] + mr * 64 + ((hi ^ (mr & 3)) * 16));
      int nr = 64 * wn + 16 * i + lo;
      bf[i] = *(const bf16x8*)(sB[cur] + nr * 64 + ((hi ^ (nr & 3)) * 16));
    }
#pragma unroll
    for (int i = 0; i < 4; ++i)
#pragma unroll
      for (int j = 0; j < 4; ++j)
        acc[i][j] = __builtin_amdgcn_mfma_f32_16x16x32_bf16(af[i], bf[j], acc[i][j], 0, 0, 0);

    __builtin_amdgcn_sched_barrier(0);
    __builtin_amdgcn_s_barrier();
  }

  float bv[4];
#pragma unroll
  for (int j = 0; j < 4; ++j) bv[j] = bias[n0 + 64 * wn + 16 * j + lo];

#pragma unroll
  for (int i = 0; i < 4; ++i)
#pragma unroll
    for (int r = 0; r < 4; ++r) {
      int m = m0 + 64 * wm + 16 * i + 4 * hi + r;
#pragma unroll
      for (int j = 0; j < 4; ++j) {
        int n = n0 + 64 * wn + 16 * j + lo;
        float val = (acc[i][j][r] + bv[j]) * scale;
        if (OUTMODE == 0) {
          ((u16*)Cout)[(size_t)m * D_ + n] = f2bf(val);
        } else if (OUTMODE == 1) {
          ((float*)Cout)[(size_t)m * D_ + n] = val;
        } else {
          int bb = m >> 11, s = m & (S_ - 1);
          int hh = n >> 6, dn = n & 63;
          ((u16*)Cout)[(((size_t)(bb * H_ + hh) * 64 + dn) << 11) + s] = f2bf(val);
        }
      }
    }
}

// ---------------- MFMA flash attention ----------------
// Block: 256 thr (4 waves), 64 q-rows; wave w owns q rows [16w,16w+16).
// K tiles of 64 keys; K LDS [key][128B], VT LDS [d][128B-of-keys], both XOR-swizzled
// via pre-swizzled global_load_lds source. Mask as u64 bitmask rows. CTX may alias Qb.
__global__ __launch_bounds__(256, 2) void attn_mfma(const u16* __restrict__ Qb,
                                                    const u16* __restrict__ Kb,
                                                    const u16* __restrict__ VT,
                                                    const unsigned long long* __restrict__ M1,
                                                    u16* __restrict__ CTX) {
  __shared__ unsigned char sQ[8192];
  __shared__ unsigned char sK[2][8192];
  __shared__ unsigned char sV[2][8192];
  __shared__ unsigned char sP[4][2048];
  const int tid = threadIdx.x, wv = tid >> 6, lane = tid & 63;
  const int hi = lane >> 4, lo = lane & 15;
  const int b = blockIdx.y >> 4, h = blockIdx.y & (H_ - 1);
  const int q0 = blockIdx.x * 64;
  const char* qg = (const char*)(Qb + ((size_t)b * S_ + q0) * D_ + h * 64);
  const char* kg = (const char*)(Kb + (size_t)b * S_ * D_ + h * 64);
  const char* vg = (const char*)(VT + ((size_t)(b * H_ + h) * 64) * S_);

  // stage one 8KB tile (64 rows x 128B), 8 chunks/row, XOR-swizzled source
  auto stage8 = [&](unsigned char* dst, const char* srcbase, size_t rs) {
#pragma unroll
    for (int p = 0; p < 2; ++p) {
      int cid = p * 4 + wv;
      int slot = cid * 64 + lane;
      int r = slot >> 3, c = slot & 7;
      gld16(srcbase + (size_t)r * rs + ((c ^ (r & 7)) * 16), dst + cid * 1024);
    }
  };

  stage8(sQ, qg, 2048);            // 2 vm
  stage8(sK[0], kg, 2048);         // 2 vm
  stage8(sV[0], vg, 4096);         // 2 vm
  asm volatile("s_waitcnt vmcnt(4)" ::: "memory");   // Q drained
  __builtin_amdgcn_s_barrier();
  __builtin_amdgcn_sched_barrier(0);

  bf16x8 qa[2];
  {
    int qr = 16 * wv + lo;
    qa[0] = *(const bf16x8*)(sQ + qr * 128 + (((0 * 4 + hi) ^ (qr & 7)) * 16));
    qa[1] = *(const bf16x8*)(sQ + qr * 128 + (((1 * 4 + hi) ^ (qr & 7)) * 16));
  }

  f32x4 acc[4];
#pragma unroll
  for (int i = 0; i < 4; ++i) acc[i] = (f32x4){0.f, 0.f, 0.f, 0.f};
  float mrow[4] = {-3e38f, -3e38f, -3e38f, -3e38f};
  float lrow[4] = {0.f, 0.f, 0.f, 0.f};
  const size_t mbase = (size_t)b * S_ * (S_ / 64);

  for (int kt = 0; kt < S_ / 64; ++kt) {
    int cur = kt & 1;
    if (kt < S_ / 64 - 1) {
      stage8(sK[cur ^ 1], kg + (size_t)(kt + 1) * 64 * 2048, 2048);
      stage8(sV[cur ^ 1], vg + (size_t)(kt + 1) * 128, 4096);
      asm volatile("s_waitcnt vmcnt(4)" ::: "memory");
    } else {
      asm volatile("s_waitcnt vmcnt(0)" ::: "memory");
    }
    __builtin_amdgcn_s_barrier();
    __builtin_amdgcn_sched_barrier(0);

    // mask words (one u64 per q-row; 16 lanes broadcast)
    unsigned long long mw[4];
#pragma unroll
    for (int r = 0; r < 4; ++r)
      mw[r] = M1[mbase + (size_t)(q0 + 16 * wv + 4 * hi + r) * (S_ / 64) + kt];

    // QK^T: 16q x 64key
    f32x4 sc[4];
#pragma unroll
    for (int nf = 0; nf < 4; ++nf) {
      int key = 16 * nf + lo;
      bf16x8 kb0 = *(const bf16x8*)(sK[cur] + key * 128 + (((0 * 4 + hi) ^ (key & 7)) * 16));
      bf16x8 kb1 = *(const bf16x8*)(sK[cur] + key * 128 + (((1 * 4 + hi) ^ (key & 7)) * 16));
      f32x4 z = (f32x4){0.f, 0.f, 0.f, 0.f};
      z = __builtin_amdgcn_mfma_f32_16x16x32_bf16(qa[0], kb0, z, 0, 0, 0);
      z = __builtin_amdgcn_mfma_f32_16x16x32_bf16(qa[1], kb1, z, 0, 0, 0);
      sc[nf] = z;
    }

    // masked online softmax (row = 4*hi+r across the 16 lanes with same hi)
#pragma unroll
    for (int r = 0; r < 4; ++r) {
      float se[4];
#pragma unroll
      for (int nf = 0; nf < 4; ++nf) {
        bool dis = (mw[r] >> (16 * nf + lo)) & 1ULL;
        se[nf] = dis ? -3e38f : sc[nf][r];
      }
      float tm = fmaxf(fmaxf(se[0], se[1]), fmaxf(se[2], se[3]));
#pragma unroll
      for (int o = 1; o < 16; o <<= 1) tm = fmaxf(tm, __shfl_xor(tm, o));
      float mnew = fmaxf(mrow[r], tm);
      float fsc = __expf(mrow[r] - mnew);
      mrow[r] = mnew;
      int qrow = 4 * hi + r;
      float rs = 0.f;
#pragma unroll
      for (int nf = 0; nf < 4; ++nf) {
        float p = (se[nf] < -1e38f) ? 0.f : __expf(se[nf] - mnew);
        rs += p;
        int off = qrow * 128 + (((16 * nf + lo) * 2) ^ ((qrow & 7) << 4));
        *(u16*)(sP[wv] + off) = f2bf(p);
      }
#pragma unroll
      for (int o = 1; o < 16; o <<= 1) rs += __shfl_xor(rs, o);
      lrow[r] = lrow[r] * fsc + rs;
#pragma unroll
      for (int nf = 0; nf < 4; ++nf) acc[nf][r] *= fsc;
    }

    asm volatile("s_waitcnt lgkmcnt(0)" ::: "memory");   // P writes visible (same wave)
    __builtin_amdgcn_sched_barrier(0);

    // PV: acc(16q x 64d) += P(16q x 64k) @ V(64k x 64d)
    bf16x8 pa0 = *(const bf16x8*)(sP[wv] + lo * 128 + (((0 * 4 + hi) ^ (lo & 7)) * 16));
    bf16x8 pa1 = *(const bf16x8*)(sP[wv] + lo * 128 + (((1 * 4 + hi) ^ (lo & 7)) * 16));
#pragma unroll
    for (int nf = 0; nf < 4; ++nf) {
      int d = 16 * nf + lo;
      bf16x8 vb0 = *(const bf16x8*)(sV[cur] + d * 128 + (((0 * 4 + hi) ^ (d & 7)) * 16));
      bf16x8 vb1 = *(const bf16x8*)(sV[cur] + d * 128 + (((1 * 4 + hi) ^ (d & 7)) * 16));
      acc[nf] = __builtin_amdgcn_mfma_f32_16x16x32_bf16(pa0, vb0, acc[nf], 0, 0, 0);
      acc[nf] = __builtin_amdgcn_mfma_f32_16x16x32_bf16(pa1, vb1, acc[nf], 0, 0, 0);
    }

    __builtin_amdgcn_sched_barrier(0);
    __builtin_amdgcn_s_barrier();
  }

  // epilogue: ctx = acc / l
#pragma unroll
  for (int r = 0; r < 4; ++r) {
    float inv = lrow[r] > 0.f ? 1.f / lrow[r] : 0.f;
    size_t row = (size_t)b * S_ + q0 + 16 * wv + 4 * hi + r;
#pragma unroll
    for (int nf = 0; nf < 4; ++nf)
      CTX[row * D_ + h * 64 + 16 * nf + lo] = f2bf(acc[nf][r] * inv);
  }
}

// ---------------- launch ----------------
extern "C" void kernel_launch(void* const* d_in, const int* in_sizes, int n_in,
                              void* d_out, int out_size, void* d_ws, size_t ws_size,
                              hipStream_t stream) {
  const float* key   = (const float*)d_in[0];
  const float* value = (const float*)d_in[1];
  const float* query = (const float*)d_in[2];
  const void*  mask  = d_in[3];
  const float* Wq = (const float*)d_in[4];
  const float* bq = (const float*)d_in[5];
  const float* Wk = (const float*)d_in[6];
  const float* bk = (const float*)d_in[7];
  const float* Wv = (const float*)d_in[8];
  const float* bv = (const float*)d_in[9];
  const float* Wo = (const float*)d_in[10];
  const float* bo = (const float*)d_in[11];

  u16* Qb  = (u16*)d_ws;                 // Q proj (bf16), later ctx (safe alias)
  u16* Kb  = Qb + NE;
  u16* VTb = Kb + NE;                    // V stored [b][h][dn][s]
  u16* Xb  = VTb + NE;                   // bf16 copy of current GEMM input
  u16* WT  = Xb + NE;                    // 4 transposed bf16 weights
  unsigned long long* M1 = (unsigned long long*)(WT + (size_t)4 * D_ * D_);
  unsigned int* flags = (unsigned int*)(M1 + (size_t)B_ * S_ * (S_ / 64));

  hipMemsetAsync(flags, 0, 8, stream);
  detect_mask_fmt<<<2048, 256, 0, stream>>>((const unsigned int*)mask, flags);
  prep_bits<<<512, 256, 0, stream>>>(mask, flags, M1);
  cvt_wT<<<dim3(512, 4), 256, 0, stream>>>(Wq, Wk, Wv, Wo, WT);

  dim3 gg(D_ / 128, (B_ * S_) / 128);    // (8, 32)
  cvt_in<<<2048, 256, 0, stream>>>((const float4*)key, (bf16x8*)Xb);
  gemm_bf16<0><<<gg, 256, 0, stream>>>(Xb, WT + (size_t)1 * D_ * D_, bk, Kb, 1.f);
  cvt_in<<<2048, 256, 0, stream>>>((const float4*)value, (bf16x8*)Xb);
  gemm_bf16<2><<<gg, 256, 0, stream>>>(Xb, WT + (size_t)2 * D_ * D_, bv, VTb, 1.f);
  cvt_in<<<2048, 256, 0, stream>>>((const float4*)query, (bf16x8*)Xb);
  gemm_bf16<0><<<gg, 256, 0, stream>>>(Xb, WT + (size_t)0 * D_ * D_, bq, Qb, 0.125f);

  attn_mfma<<<dim3(S_ / 64, B_ * H_), 256, 0, stream>>>(Qb, Kb, VTb, M1, Qb);

  gemm_bf16<1><<<gg, 256, 0, stream>>>(Qb, WT + (size_t)3 * D_ * D_, bo, d_out, 1.f);
}

// Round 3
// 382.703 us; speedup vs baseline: 3.6097x; 1.2849x over previous
//
#include <hip/hip_runtime.h>
#include <hip/hip_bf16.h>
#include <cstdint>

#define B_   2
#define S_   2048
#define D_   1024
#define H_   16
#define DPH_ 64
#define NT_  (S_ / 64)

typedef float f32x4 __attribute__((ext_vector_type(4)));
typedef short bf16x8 __attribute__((ext_vector_type(8)));
typedef unsigned short u16;

static const size_t NE = (size_t)B_ * S_ * D_;   // 4,194,304 elements
static const size_t DD = (size_t)D_ * D_;

__device__ __forceinline__ u16 f2bf(float f) {
  union { float f; unsigned u; } cv; cv.f = f;
  unsigned u = cv.u;
  return (u16)((u + 0x7fffu + ((u >> 16) & 1u)) >> 16);
}

__device__ __forceinline__ unsigned cvtpk(float a, float b) {
  unsigned r;
  asm("v_cvt_pk_bf16_f32 %0, %1, %2" : "=v"(r) : "v"(a), "v"(b));
  return r;
}

__device__ __forceinline__ void gld16(const void* g, void* l) {
  __builtin_amdgcn_global_load_lds((const __attribute__((address_space(1))) unsigned int*)g,
                                   (__attribute__((address_space(3))) unsigned int*)l, 16, 0, 0);
}

// ---------------- mask format detection ----------------
__global__ __launch_bounds__(256) void detect_mask_fmt(const unsigned int* __restrict__ m,
                                                       unsigned int* __restrict__ flags) {
  int i = blockIdx.x * 256 + threadIdx.x;
  unsigned a = 0, b = 0;
#pragma unroll
  for (int p = 0; p < 4; ++p) {
    unsigned v = m[(size_t)i * 4 + p];
    if (v > 1u) a = 1u;
    if (v != 0u && v != 0x3f800000u) b = 1u;
  }
  if (a) atomicOr(&flags[0], 1u);
  if (b) atomicOr(&flags[1], 1u);
}

// ---------------- mask -> bitmask: M1[b][q][w] u64, bit k = disallowed ----------------
__device__ __forceinline__ unsigned nz4(unsigned w) {
  unsigned r = 0;
  if (w & 0x000000ffu) r |= 1u;
  if (w & 0x0000ff00u) r |= 2u;
  if (w & 0x00ff0000u) r |= 4u;
  if (w & 0xff000000u) r |= 8u;
  return r;
}

__global__ __launch_bounds__(256) void prep_bits(const void* __restrict__ src,
                                                 const unsigned int* __restrict__ flags,
                                                 unsigned long long* __restrict__ dst) {
  int i = blockIdx.x * 256 + threadIdx.x;
  unsigned long long w = 0;
  bool fourB = (flags[0] == 0u) || (flags[1] == 0u);
  if (fourB) {
    const uint4* p = (const uint4*)src + (size_t)i * 16;
#pragma unroll
    for (int j = 0; j < 16; ++j) {
      uint4 v = p[j];
      unsigned bits = (v.x ? 1u : 0u) | (v.y ? 2u : 0u) | (v.z ? 4u : 0u) | (v.w ? 8u : 0u);
      w |= (unsigned long long)bits << (j * 4);
    }
  } else {
    const uint4* p = (const uint4*)src + (size_t)i * 4;
#pragma unroll
    for (int j = 0; j < 4; ++j) {
      uint4 v = p[j];
      w |= (unsigned long long)nz4(v.x) << (j * 16 + 0);
      w |= (unsigned long long)nz4(v.y) << (j * 16 + 4);
      w |= (unsigned long long)nz4(v.z) << (j * 16 + 8);
      w |= (unsigned long long)nz4(v.w) << (j * 16 + 12);
    }
  }
  dst[i] = w;
}

// ---------------- fused f32 -> bf16 for all three inputs ----------------
__global__ __launch_bounds__(256) void cvt3(const float4* __restrict__ k, const float4* __restrict__ v,
                                            const float4* __restrict__ q,
                                            bf16x8* __restrict__ xk, bf16x8* __restrict__ xv,
                                            bf16x8* __restrict__ xq) {
  int bid = blockIdx.x;
  int which = bid >> 11;                       // 2048 blocks per tensor
  int i = (bid & 2047) * 256 + threadIdx.x;
  const float4* s = (which == 0) ? k : (which == 1) ? v : q;
  bf16x8* d = (which == 0) ? xk : (which == 1) ? xv : xq;
  float4 a = s[(size_t)i * 2], c = s[(size_t)i * 2 + 1];
  bf16x8 o;
  o[0] = (short)f2bf(a.x); o[1] = (short)f2bf(a.y);
  o[2] = (short)f2bf(a.z); o[3] = (short)f2bf(a.w);
  o[4] = (short)f2bf(c.x); o[5] = (short)f2bf(c.y);
  o[6] = (short)f2bf(c.z); o[7] = (short)f2bf(c.w);
  d[i] = o;
}

// ---------------- weight transpose + convert: WT[n][k] = bf16(W[k][n]) ----------------
__global__ __launch_bounds__(256) void cvt_wT(const float* __restrict__ Wq, const float* __restrict__ Wk,
                                              const float* __restrict__ Wv, const float* __restrict__ Wo,
                                              u16* __restrict__ WT) {
  const float* W = (blockIdx.y == 0) ? Wq : (blockIdx.y == 1) ? Wk : (blockIdx.y == 2) ? Wv : Wo;
  u16* O = WT + (size_t)blockIdx.y * DD;
  int t = blockIdx.x * 256 + threadIdx.x;
  int n = t & 1023, k8 = (t >> 10) << 3;
  bf16x8 v;
#pragma unroll
  for (int j = 0; j < 8; ++j) v[j] = (short)f2bf(W[(size_t)(k8 + j) * D_ + n]);
  *(bf16x8*)(O + (size_t)n * D_ + k8) = v;
}

// ---------------- bf16 MFMA GEMM: C = scale*(A @ WT^T + bias) ----------------
// mode 0: bf16 out [M][1024]; 1: f32 out; 2: bf16 VT[b][h][dn][s] via LDS transpose.
struct GArgs {
  const u16* A[3]; const u16* W[3]; const float* bias[3];
  void* C[3]; float scale[3]; int mode[3];
};

__global__ __launch_bounds__(256, 3) void gemm_bf16(GArgs ga) {
  __shared__ unsigned char smem[32768];        // sA dbuf 16K | sB dbuf 16K (reused for mode2)
  const int z = blockIdx.z;
  const u16* A = ga.A[z]; const u16* WT = ga.W[z]; const float* bias = ga.bias[z];
  void* Cout = ga.C[z]; const float scale = ga.scale[z]; const int mode = ga.mode[z];

  const int tid = threadIdx.x, wv = tid >> 6, lane = tid & 63;
  const int hi = lane >> 4, lo = lane & 15;
  const int wm = wv >> 1, wn = wv & 1;
  const int m0 = blockIdx.y * 128, n0 = blockIdx.x * 128;
  const char* ag = (const char*)A + (size_t)m0 * 2048;
  const char* bg = (const char*)WT + (size_t)n0 * 2048;

  f32x4 acc[4][4];
#pragma unroll
  for (int i = 0; i < 4; ++i)
#pragma unroll
    for (int j = 0; j < 4; ++j) acc[i][j] = (f32x4){0.f, 0.f, 0.f, 0.f};

  auto stageg = [&](unsigned char* dst, const char* srcbase, int koff) {
#pragma unroll
    for (int p = 0; p < 2; ++p) {
      int cid = p * 4 + wv;
      int slot = cid * 64 + lane;
      int r = slot >> 2, c = slot & 3;
      gld16(srcbase + (size_t)r * 2048 + koff + ((c ^ (r & 3)) * 16), dst + cid * 1024);
    }
  };

  stageg(smem, ag, 0);
  stageg(smem + 16384, bg, 0);

  for (int kt = 0; kt < 32; ++kt) {
    int cur = kt & 1;
    unsigned char* sA = smem + cur * 8192;
    unsigned char* sB = smem + 16384 + cur * 8192;
    if (kt < 31) {
      stageg(smem + (cur ^ 1) * 8192, ag, (kt + 1) * 64);
      stageg(smem + 16384 + (cur ^ 1) * 8192, bg, (kt + 1) * 64);
      asm volatile("s_waitcnt vmcnt(4)" ::: "memory");
    } else {
      asm volatile("s_waitcnt vmcnt(0)" ::: "memory");
    }
    __builtin_amdgcn_s_barrier();
    __builtin_amdgcn_sched_barrier(0);

    bf16x8 af[4], bf[4];
#pragma unroll
    for (int i = 0; i < 4; ++i) {
      int mr = 64 * wm + 16 * i + lo;
      af[i] = *(const bf16x8*)(sA + mr * 64 + ((hi ^ (mr & 3)) * 16));
      int nr = 64 * wn + 16 * i + lo;
      bf[i] = *(const bf16x8*)(sB + nr * 64 + ((hi ^ (nr & 3)) * 16));
    }
#pragma unroll
    for (int i = 0; i < 4; ++i)
#pragma unroll
      for (int j = 0; j < 4; ++j)
        acc[i][j] = __builtin_amdgcn_mfma_f32_16x16x32_bf16(af[i], bf[j], acc[i][j], 0, 0, 0);

    __builtin_amdgcn_sched_barrier(0);
    __builtin_amdgcn_s_barrier();
  }

  float bv[4];
#pragma unroll
  for (int j = 0; j < 4; ++j) bv[j] = bias[n0 + 64 * wn + 16 * j + lo];

  if (mode <= 1) {
#pragma unroll
    for (int i = 0; i < 4; ++i)
#pragma unroll
      for (int r = 0; r < 4; ++r) {
        int m = m0 + 64 * wm + 16 * i + 4 * hi + r;
#pragma unroll
        for (int j = 0; j < 4; ++j) {
          int n = n0 + 64 * wn + 16 * j + lo;
          float val = (acc[i][j][r] + bv[j]) * scale;
          if (mode == 0) ((u16*)Cout)[(size_t)m * D_ + n] = f2bf(val);
          else           ((float*)Cout)[(size_t)m * D_ + n] = val;
        }
      }
  } else {
    // V: transpose 128x128 tile through LDS, write VT[b][h][dn][s] coalesced
    __syncthreads();
#pragma unroll
    for (int i = 0; i < 4; ++i) {
      int mb2 = 64 * wm + 16 * i + 4 * hi;     // local m base (4 consecutive)
#pragma unroll
      for (int j = 0; j < 4; ++j) {
        int n = 64 * wn + 16 * j + lo;         // local n
        unsigned w0 = (unsigned)f2bf(acc[i][j][0] + bv[j]) | ((unsigned)f2bf(acc[i][j][1] + bv[j]) << 16);
        unsigned w1 = (unsigned)f2bf(acc[i][j][2] + bv[j]) | ((unsigned)f2bf(acc[i][j][3] + bv[j]) << 16);
        unsigned byteoff = n * 256 + ((2 * mb2) ^ ((n & 7) << 5));
        *(uint2*)(smem + byteoff) = make_uint2(w0, w1);
      }
    }
    __syncthreads();
    int nl = tid >> 1, half = tid & 1;
    unsigned ob[32];
#pragma unroll
    for (int s = 0; s < 16; ++s) {
      unsigned byteoff = nl * 256 + ((128 * half + 8 * s) ^ ((nl & 7) << 5));
      uint2 vv = *(const uint2*)(smem + byteoff);
      ob[2 * s] = vv.x; ob[2 * s + 1] = vv.y;
    }
    int bb = blockIdx.y >> 4;
    int habs = blockIdx.x * 2 + (nl >> 6);
    int dn = nl & 63;
    size_t sg = (size_t)(blockIdx.y & 15) * 128 + half * 64;
    u16* outp = (u16*)Cout + ((size_t)(bb * H_ + habs) * 64 + dn) * 2048 + sg;
#pragma unroll
    for (int c2 = 0; c2 < 8; ++c2)
      *(uint4*)(outp + c2 * 8) = *(uint4*)&ob[4 * c2];
  }
}

// ---------------- MFMA flash attention, swapped-operand / in-lane softmax ----------------
// 4 waves x 16 q-rows; scores via mfma(K,Q) -> lane owns one q-row (q = 16wv+lo).
// PV via mfma(V^T, P) -> acc is ctx^T (d per reg, q per lane). CTX may alias Qb.
__global__ __launch_bounds__(256, 4) void attn_mfma2(const u16* __restrict__ Qb,
                                                     const u16* __restrict__ Kb,
                                                     const u16* __restrict__ VT,
                                                     const unsigned long long* __restrict__ M1,
                                                     u16* __restrict__ CTX) {
  __shared__ unsigned char sK[2][8192];
  __shared__ unsigned char sV[2][8192];
  __shared__ unsigned char sP[4][2048];        // per-wave pair-major P, swizzled
  const int tid = threadIdx.x, wv = tid >> 6, lane = tid & 63;
  const int hi = lane >> 4, lo = lane & 15;
  const int b = blockIdx.y >> 4, h = blockIdx.y & (H_ - 1);
  const int q0 = blockIdx.x * 64;
  const char* kg = (const char*)(Kb + (size_t)b * S_ * D_ + h * 64);
  const char* vg = (const char*)(VT + ((size_t)(b * H_ + h) * 64) * S_);
  unsigned* sPw = (unsigned*)sP[wv];

  // Q fragments straight to registers (row q = q0+16wv+lo, scaled by 0.125*log2e upstream)
  const u16* qrow = Qb + ((size_t)b * S_ + q0 + 16 * wv + lo) * D_ + h * 64;
  bf16x8 qa0 = *(const bf16x8*)(qrow + 8 * hi);
  bf16x8 qa1 = *(const bf16x8*)(qrow + 32 + 8 * hi);

  auto stage8 = [&](unsigned char* dst, const char* srcbase, size_t rs) {
#pragma unroll
    for (int p = 0; p < 2; ++p) {
      int cid = p * 4 + wv;
      int slot = cid * 64 + lane;
      int r = slot >> 3, c = slot & 7;
      gld16(srcbase + (size_t)r * rs + ((c ^ (r & 7)) * 16), dst + cid * 1024);
    }
  };

  stage8(sK[0], kg, 2048);
  stage8(sV[0], vg, 4096);

  f32x4 acc[4];
#pragma unroll
  for (int i = 0; i < 4; ++i) acc[i] = (f32x4){0.f, 0.f, 0.f, 0.f};
  float mrow = -3e38f, lrow = 0.f;
  const unsigned long long* mrp = M1 + ((size_t)b * S_ + q0 + 16 * wv + lo) * NT_;

  for (int kt = 0; kt < NT_; ++kt) {
    int cur = kt & 1;
    if (kt < NT_ - 1) {
      stage8(sK[cur ^ 1], kg + (size_t)(kt + 1) * 64 * 2048, 2048);
      stage8(sV[cur ^ 1], vg + (size_t)(kt + 1) * 128, 4096);
      asm volatile("s_waitcnt vmcnt(4)" ::: "memory");
    } else {
      asm volatile("s_waitcnt vmcnt(0)" ::: "memory");
    }
    __builtin_amdgcn_s_barrier();
    __builtin_amdgcn_sched_barrier(0);

    unsigned long long mw = mrp[kt] >> (unsigned)(4 * hi);

    // QK^T swapped: sc[nf][reg] = S[key=16nf+4hi+reg][q=16wv+lo]
    f32x4 sc[4];
#pragma unroll
    for (int nf = 0; nf < 4; ++nf) {
      int key = 16 * nf + lo;
      bf16x8 kb0 = *(const bf16x8*)(sK[cur] + key * 128 + (((0 + hi) ^ (key & 7)) * 16));
      bf16x8 kb1 = *(const bf16x8*)(sK[cur] + key * 128 + (((4 + hi) ^ (key & 7)) * 16));
      f32x4 z = (f32x4){0.f, 0.f, 0.f, 0.f};
      z = __builtin_amdgcn_mfma_f32_16x16x32_bf16(kb0, qa0, z, 0, 0, 0);
      z = __builtin_amdgcn_mfma_f32_16x16x32_bf16(kb1, qa1, z, 0, 0, 0);
      sc[nf] = z;
    }

    // in-lane row max (raw scores = valid upper bound)
    float t0 = fmaxf(fmaxf(sc[0][0], sc[0][1]), fmaxf(sc[0][2], sc[0][3]));
    float t1 = fmaxf(fmaxf(sc[1][0], sc[1][1]), fmaxf(sc[1][2], sc[1][3]));
    float t2 = fmaxf(fmaxf(sc[2][0], sc[2][1]), fmaxf(sc[2][2], sc[2][3]));
    float t3 = fmaxf(fmaxf(sc[3][0], sc[3][1]), fmaxf(sc[3][2], sc[3][3]));
    float tm = fmaxf(fmaxf(t0, t1), fmaxf(t2, t3));
    tm = fmaxf(tm, __shfl_xor(tm, 16));
    tm = fmaxf(tm, __shfl_xor(tm, 32));
    float mnew = fmaxf(mrow, tm);
    float fsc = __builtin_amdgcn_exp2f(mrow - mnew);
    mrow = mnew;

    unsigned nlo = ~(unsigned)mw;
    unsigned nhi = ~(unsigned)(mw >> 32);
    float p[4][4];
#pragma unroll
    for (int nf = 0; nf < 4; ++nf) {
      unsigned hf = (nf < 2) ? nlo : nhi;
#pragma unroll
      for (int r = 0; r < 4; ++r) {
        float e = __builtin_amdgcn_exp2f(sc[nf][r] - mnew);
        int keep = ((int)(hf << (31 - (16 * (nf & 1) + r)))) >> 31;
        p[nf][r] = __uint_as_float(__float_as_uint(e) & (unsigned)keep);
      }
    }
    float s0 = (p[0][0] + p[0][1]) + (p[0][2] + p[0][3]);
    float s1 = (p[1][0] + p[1][1]) + (p[1][2] + p[1][3]);
    float s2 = (p[2][0] + p[2][1]) + (p[2][2] + p[2][3]);
    float s3 = (p[3][0] + p[3][1]) + (p[3][2] + p[3][3]);
    float rs = (s0 + s1) + (s2 + s3);
    rs += __shfl_xor(rs, 16);
    rs += __shfl_xor(rs, 32);
    lrow = lrow * fsc + rs;
#pragma unroll
    for (int nd = 0; nd < 4; ++nd) acc[nd] *= fsc;

    // pack P pairs -> per-wave LDS (pair-major [q=lo][kp], XOR swizzle, no barrier needed)
#pragma unroll
    for (int nf = 0; nf < 4; ++nf) {
      unsigned w0 = cvtpk(p[nf][0], p[nf][1]);
      unsigned w1 = cvtpk(p[nf][2], p[nf][3]);
      int dw = lo * 32 + ((8 * nf + 2 * hi) ^ ((lo & 7) << 2));
      *(uint2*)(sPw + dw) = make_uint2(w0, w1);
    }

    // PV: acc[nd] (d=16nd+4hi+reg, q=lo) += V^T chunk . P chunk
#pragma unroll
    for (int mh = 0; mh < 2; ++mh) {
      bf16x8 pf = *(const bf16x8*)(sPw + (lo * 32 + ((16 * mh + 4 * hi) ^ ((lo & 7) << 2))));
#pragma unroll
      for (int nd = 0; nd < 4; ++nd) {
        int d = 16 * nd + lo;
        bf16x8 vb = *(const bf16x8*)(sV[cur] + d * 128 + (((4 * mh + hi) ^ (d & 7)) * 16));
        acc[nd] = __builtin_amdgcn_mfma_f32_16x16x32_bf16(vb, pf, acc[nd], 0, 0, 0);
      }
    }

    __builtin_amdgcn_sched_barrier(0);
    __builtin_amdgcn_s_barrier();
  }

  float inv = lrow > 0.f ? 1.f / lrow : 0.f;
  u16* crow = CTX + ((size_t)b * S_ + q0 + 16 * wv + lo) * D_ + h * 64;
#pragma unroll
  for (int nd = 0; nd < 4; ++nd) {
    unsigned w0 = (unsigned)f2bf(acc[nd][0] * inv) | ((unsigned)f2bf(acc[nd][1] * inv) << 16);
    unsigned w1 = (unsigned)f2bf(acc[nd][2] * inv) | ((unsigned)f2bf(acc[nd][3] * inv) << 16);
    *(uint2*)(crow + 16 * nd + 4 * hi) = make_uint2(w0, w1);
  }
}

// ---------------- launch ----------------
extern "C" void kernel_launch(void* const* d_in, const int* in_sizes, int n_in,
                              void* d_out, int out_size, void* d_ws, size_t ws_size,
                              hipStream_t stream) {
  const float* key   = (const float*)d_in[0];
  const float* value = (const float*)d_in[1];
  const float* query = (const float*)d_in[2];
  const void*  mask  = d_in[3];
  const float* Wq = (const float*)d_in[4];
  const float* bq = (const float*)d_in[5];
  const float* Wk = (const float*)d_in[6];
  const float* bk = (const float*)d_in[7];
  const float* Wv = (const float*)d_in[8];
  const float* bv = (const float*)d_in[9];
  const float* Wo = (const float*)d_in[10];
  const float* bo = (const float*)d_in[11];

  u16* Qb  = (u16*)d_ws;                 // Q proj (bf16), later ctx (safe alias)
  u16* Kb  = Qb + NE;
  u16* VTb = Kb + NE;                    // V stored [b][h][dn][s]
  u16* Xq  = VTb + NE;
  u16* Xk  = Xq + NE;
  u16* Xv  = Xk + NE;
  u16* WT  = Xv + NE;                    // 4 transposed bf16 weights
  unsigned long long* M1 = (unsigned long long*)(WT + 4 * DD);
  unsigned int* flags = (unsigned int*)(M1 + (size_t)B_ * S_ * NT_);

  hipMemsetAsync(flags, 0, 8, stream);
  detect_mask_fmt<<<2048, 256, 0, stream>>>((const unsigned int*)mask, flags);
  prep_bits<<<512, 256, 0, stream>>>(mask, flags, M1);
  cvt_wT<<<dim3(512, 4), 256, 0, stream>>>(Wq, Wk, Wv, Wo, WT);
  cvt3<<<6144, 256, 0, stream>>>((const float4*)key, (const float4*)value, (const float4*)query,
                                 (bf16x8*)Xk, (bf16x8*)Xv, (bf16x8*)Xq);

  const float QSCALE = 0.125f * 1.4426950408889634f;   // 1/sqrt(64) * log2(e)
  GArgs g3;
  g3.A[0] = Xq; g3.W[0] = WT + 0 * DD; g3.bias[0] = bq; g3.C[0] = Qb;  g3.scale[0] = QSCALE; g3.mode[0] = 0;
  g3.A[1] = Xk; g3.W[1] = WT + 1 * DD; g3.bias[1] = bk; g3.C[1] = Kb;  g3.scale[1] = 1.f;    g3.mode[1] = 0;
  g3.A[2] = Xv; g3.W[2] = WT + 2 * DD; g3.bias[2] = bv; g3.C[2] = VTb; g3.scale[2] = 1.f;    g3.mode[2] = 2;
  gemm_bf16<<<dim3(D_ / 128, (B_ * S_) / 128, 3), 256, 0, stream>>>(g3);

  attn_mfma2<<<dim3(S_ / 64, B_ * H_), 256, 0, stream>>>(Qb, Kb, VTb, M1, Qb);

  GArgs go;
  go.A[0] = Qb; go.W[0] = WT + 3 * DD; go.bias[0] = bo; go.C[0] = d_out; go.scale[0] = 1.f; go.mode[0] = 1;
  go.A[1] = Qb; go.W[1] = WT + 3 * DD; go.bias[1] = bo; go.C[1] = d_out; go.scale[1] = 1.f; go.mode[1] = 1;
  go.A[2] = Qb; go.W[2] = WT + 3 * DD; go.bias[2] = bo; go.C[2] = d_out; go.scale[2] = 1.f; go.mode[2] = 1;
  gemm_bf16<<<dim3(D_ / 128, (B_ * S_) / 128, 1), 256, 0, stream>>>(go);
}

// Round 5
// 291.279 us; speedup vs baseline: 4.7426x; 1.3139x over previous
//
#include <hip/hip_runtime.h>
#include <hip/hip_bf16.h>
#include <cstdint>

#define B_   2
#define S_   2048
#define D_   1024
#define H_   16
#define DPH_ 64
#define NT_  (S_ / 64)

typedef float f32x4 __attribute__((ext_vector_type(4)));
typedef short bf16x8 __attribute__((ext_vector_type(8)));
typedef unsigned short u16;

static const size_t NE = (size_t)B_ * S_ * D_;   // 4,194,304 elements
static const size_t DD = (size_t)D_ * D_;

__device__ __forceinline__ u16 f2bf(float f) {
  union { float f; unsigned u; } cv; cv.f = f;
  unsigned u = cv.u;
  return (u16)((u + 0x7fffu + ((u >> 16) & 1u)) >> 16);
}

__device__ __forceinline__ unsigned cvtpk(float a, float b) {
  unsigned r;
  asm("v_cvt_pk_bf16_f32 %0, %1, %2" : "=v"(r) : "v"(a), "v"(b));
  return r;
}

__device__ __forceinline__ void gld16(const void* g, void* l) {
  __builtin_amdgcn_global_load_lds((const __attribute__((address_space(1))) unsigned int*)g,
                                   (__attribute__((address_space(3))) unsigned int*)l, 16, 0, 0);
}

// ---------------- mask format detection (512KB scan, wave-reduced, plain stores) ----------------
// flags[0]=1: some word >1            -> not int32{0,1} data
// flags[1]=1: some word not in {0,1.0f} -> not float32 data
__global__ __launch_bounds__(256) void detect_mask_fmt(const uint4* __restrict__ m,
                                                       unsigned int* __restrict__ flags) {
  int i = blockIdx.x * 256 + threadIdx.x;
  uint4 v = m[i];
  int a = (v.x > 1u) | (v.y > 1u) | (v.z > 1u) | (v.w > 1u);
  int bb = ((v.x != 0u && v.x != 0x3f800000u) | (v.y != 0u && v.y != 0x3f800000u) |
            (v.z != 0u && v.z != 0x3f800000u) | (v.w != 0u && v.w != 0x3f800000u));
  int anyA = __any(a), anyB = __any(bb);
  if ((threadIdx.x & 63) == 0) {
    if (anyA) flags[0] = 1u;       // idempotent racy store; pre-zeroed by memset
    if (anyB) flags[1] = 1u;
  }
}

// ---------------- mask -> bitmask: M1[b][q][w] u64, bit k = disallowed ----------------
__device__ __forceinline__ unsigned nz4(unsigned w) {
  unsigned r = 0;
  if (w & 0x000000ffu) r |= 1u;
  if (w & 0x0000ff00u) r |= 2u;
  if (w & 0x00ff0000u) r |= 4u;
  if (w & 0xff000000u) r |= 8u;
  return r;
}

__global__ __launch_bounds__(256) void prep_bits(const void* __restrict__ src,
                                                 const unsigned int* __restrict__ flags,
                                                 unsigned long long* __restrict__ dst) {
  int i = blockIdx.x * 256 + threadIdx.x;
  unsigned long long w = 0;
  bool fourB = (flags[0] == 0u) || (flags[1] == 0u);
  if (fourB) {
    const uint4* p = (const uint4*)src + (size_t)i * 16;
#pragma unroll
    for (int j = 0; j < 16; ++j) {
      uint4 v = p[j];
      unsigned bits = (v.x ? 1u : 0u) | (v.y ? 2u : 0u) | (v.z ? 4u : 0u) | (v.w ? 8u : 0u);
      w |= (unsigned long long)bits << (j * 4);
    }
  } else {
    const uint4* p = (const uint4*)src + (size_t)i * 4;
#pragma unroll
    for (int j = 0; j < 4; ++j) {
      uint4 v = p[j];
      w |= (unsigned long long)nz4(v.x) << (j * 16 + 0);
      w |= (unsigned long long)nz4(v.y) << (j * 16 + 4);
      w |= (unsigned long long)nz4(v.z) << (j * 16 + 8);
      w |= (unsigned long long)nz4(v.w) << (j * 16 + 12);
    }
  }
  dst[i] = w;
}

// ---------------- fused f32->bf16: 3 inputs (blocks 0..6143) + 4 weight transposes ----------------
__global__ __launch_bounds__(256) void cvt_all(const float4* __restrict__ k, const float4* __restrict__ v,
                                               const float4* __restrict__ q,
                                               bf16x8* __restrict__ xk, bf16x8* __restrict__ xv,
                                               bf16x8* __restrict__ xq,
                                               const float* __restrict__ Wq, const float* __restrict__ Wk,
                                               const float* __restrict__ Wv, const float* __restrict__ Wo,
                                               u16* __restrict__ WT) {
  int bid = blockIdx.x;
  if (bid < 6144) {
    int which = bid >> 11;
    int i = (bid & 2047) * 256 + threadIdx.x;
    const float4* s = (which == 0) ? k : (which == 1) ? v : q;
    bf16x8* d = (which == 0) ? xk : (which == 1) ? xv : xq;
    float4 a = s[(size_t)i * 2], c = s[(size_t)i * 2 + 1];
    bf16x8 o;
    o[0] = (short)f2bf(a.x); o[1] = (short)f2bf(a.y);
    o[2] = (short)f2bf(a.z); o[3] = (short)f2bf(a.w);
    o[4] = (short)f2bf(c.x); o[5] = (short)f2bf(c.y);
    o[6] = (short)f2bf(c.z); o[7] = (short)f2bf(c.w);
    d[i] = o;
  } else {
    int idx2 = bid - 6144;                       // [0,2048)
    int mat = idx2 >> 9;
    const float* W = (mat == 0) ? Wq : (mat == 1) ? Wk : (mat == 2) ? Wv : Wo;
    u16* O = WT + (size_t)mat * DD;
    int t = (idx2 & 511) * 256 + threadIdx.x;    // [0,131072)
    int n = t & 1023, k8 = (t >> 10) << 3;
    bf16x8 o;
#pragma unroll
    for (int j = 0; j < 8; ++j) o[j] = (short)f2bf(W[(size_t)(k8 + j) * D_ + n]);
    *(bf16x8*)(O + (size_t)n * D_ + k8) = o;
  }
}

// ---------------- bf16 MFMA GEMM: C = scale*(A @ WT^T + bias) ----------------
// mode 0: bf16 out [M][1024]; 1: f32 out; 2: bf16 VT[b][h][dn][s] via LDS transpose.
struct GArgs {
  const u16* A[3]; const u16* W[3]; const float* bias[3];
  void* C[3]; float scale[3]; int mode[3];
};

__global__ __launch_bounds__(256, 3) void gemm_bf16(GArgs ga) {
  __shared__ unsigned char smem[32768];        // sA dbuf 16K | sB dbuf 16K (reused for mode2)
  const int z = blockIdx.z;
  const u16* A = ga.A[z]; const u16* WT = ga.W[z]; const float* bias = ga.bias[z];
  void* Cout = ga.C[z]; const float scale = ga.scale[z]; const int mode = ga.mode[z];

  const int tid = threadIdx.x, wv = tid >> 6, lane = tid & 63;
  const int hi = lane >> 4, lo = lane & 15;
  const int wm = wv >> 1, wn = wv & 1;
  const int m0 = blockIdx.y * 128, n0 = blockIdx.x * 128;
  const char* ag = (const char*)A + (size_t)m0 * 2048;
  const char* bg = (const char*)WT + (size_t)n0 * 2048;

  f32x4 acc[4][4];
#pragma unroll
  for (int i = 0; i < 4; ++i)
#pragma unroll
    for (int j = 0; j < 4; ++j) acc[i][j] = (f32x4){0.f, 0.f, 0.f, 0.f};

  auto stageg = [&](unsigned char* dst, const char* srcbase, int koff) {
#pragma unroll
    for (int p = 0; p < 2; ++p) {
      int cid = p * 4 + wv;
      int slot = cid * 64 + lane;
      int r = slot >> 2, c = slot & 3;
      gld16(srcbase + (size_t)r * 2048 + koff + ((c ^ (r & 3)) * 16), dst + cid * 1024);
    }
  };

  stageg(smem, ag, 0);
  stageg(smem + 16384, bg, 0);

  for (int kt = 0; kt < 32; ++kt) {
    int cur = kt & 1;
    unsigned char* sA = smem + cur * 8192;
    unsigned char* sB = smem + 16384 + cur * 8192;
    if (kt < 31) {
      stageg(smem + (cur ^ 1) * 8192, ag, (kt + 1) * 64);
      stageg(smem + 16384 + (cur ^ 1) * 8192, bg, (kt + 1) * 64);
      asm volatile("s_waitcnt vmcnt(4)" ::: "memory");
    } else {
      asm volatile("s_waitcnt vmcnt(0)" ::: "memory");
    }
    __builtin_amdgcn_s_barrier();
    __builtin_amdgcn_sched_barrier(0);

    bf16x8 af[4], bf[4];
#pragma unroll
    for (int i = 0; i < 4; ++i) {
      int mr = 64 * wm + 16 * i + lo;
      af[i] = *(const bf16x8*)(sA + mr * 64 + ((hi ^ (mr & 3)) * 16));
      int nr = 64 * wn + 16 * i + lo;
      bf[i] = *(const bf16x8*)(sB + nr * 64 + ((hi ^ (nr & 3)) * 16));
    }
#pragma unroll
    for (int i = 0; i < 4; ++i)
#pragma unroll
      for (int j = 0; j < 4; ++j)
        acc[i][j] = __builtin_amdgcn_mfma_f32_16x16x32_bf16(af[i], bf[j], acc[i][j], 0, 0, 0);

    __builtin_amdgcn_sched_barrier(0);
    __builtin_amdgcn_s_barrier();
  }

  float bv[4];
#pragma unroll
  for (int j = 0; j < 4; ++j) bv[j] = bias[n0 + 64 * wn + 16 * j + lo];

  if (mode <= 1) {
#pragma unroll
    for (int i = 0; i < 4; ++i)
#pragma unroll
      for (int r = 0; r < 4; ++r) {
        int m = m0 + 64 * wm + 16 * i + 4 * hi + r;
#pragma unroll
        for (int j = 0; j < 4; ++j) {
          int n = n0 + 64 * wn + 16 * j + lo;
          float val = (acc[i][j][r] + bv[j]) * scale;
          if (mode == 0) ((u16*)Cout)[(size_t)m * D_ + n] = f2bf(val);
          else           ((float*)Cout)[(size_t)m * D_ + n] = val;
        }
      }
  } else {
    // V: transpose 128x128 tile through LDS, write VT[b][h][dn][s] coalesced
    __syncthreads();
#pragma unroll
    for (int i = 0; i < 4; ++i) {
      int mb2 = 64 * wm + 16 * i + 4 * hi;
#pragma unroll
      for (int j = 0; j < 4; ++j) {
        int n = 64 * wn + 16 * j + lo;
        unsigned w0 = (unsigned)f2bf(acc[i][j][0] + bv[j]) | ((unsigned)f2bf(acc[i][j][1] + bv[j]) << 16);
        unsigned w1 = (unsigned)f2bf(acc[i][j][2] + bv[j]) | ((unsigned)f2bf(acc[i][j][3] + bv[j]) << 16);
        unsigned byteoff = n * 256 + ((2 * mb2) ^ ((n & 7) << 5));
        *(uint2*)(smem + byteoff) = make_uint2(w0, w1);
      }
    }
    __syncthreads();
    int nl = tid >> 1, half = tid & 1;
    unsigned ob[32];
#pragma unroll
    for (int s = 0; s < 16; ++s) {
      unsigned byteoff = nl * 256 + ((128 * half + 8 * s) ^ ((nl & 7) << 5));
      uint2 vv = *(const uint2*)(smem + byteoff);
      ob[2 * s] = vv.x; ob[2 * s + 1] = vv.y;
    }
    int bb = blockIdx.y >> 4;
    int habs = blockIdx.x * 2 + (nl >> 6);
    int dn = nl & 63;
    size_t sg = (size_t)(blockIdx.y & 15) * 128 + half * 64;
    u16* outp = (u16*)Cout + ((size_t)(bb * H_ + habs) * 64 + dn) * 2048 + sg;
#pragma unroll
    for (int c2 = 0; c2 < 8; ++c2)
      *(uint4*)(outp + c2 * 8) = *(uint4*)&ob[4 * c2];
  }
}

// ---------------- MFMA flash attention, 128 q-rows/block, swapped-operand softmax ----------------
// 4 waves x 32 q-rows (2 halves of 16). scores via mfma(K,Q): lane owns q-rows (lo, 16+lo).
// PV via mfma(V^T,P): acc is ctx^T (d per reg, q per lane). CTX may alias Qb.
__global__ __launch_bounds__(256, 3) void attn_mfma2(const u16* __restrict__ Qb,
                                                     const u16* __restrict__ Kb,
                                                     const u16* __restrict__ VT,
                                                     const unsigned long long* __restrict__ M1,
                                                     u16* __restrict__ CTX) {
  __shared__ unsigned char sK[2][8192];
  __shared__ unsigned char sV[2][8192];
  __shared__ unsigned char sP[4][4096];        // per-wave pair-major P (32q x 64k), swizzled
  const int tid = threadIdx.x, wv = tid >> 6, lane = tid & 63;
  const int hi = lane >> 4, lo = lane & 15;
  const int b = blockIdx.y >> 4, h = blockIdx.y & (H_ - 1);
  const int q0 = blockIdx.x * 128;
  const char* kg = (const char*)(Kb + (size_t)b * S_ * D_ + h * 64);
  const char* vg = (const char*)(VT + ((size_t)(b * H_ + h) * 64) * S_);
  unsigned* sPw = (unsigned*)sP[wv];

  // Q fragments straight to registers (rows q0+32wv+lo and +16; scaled by 0.125*log2e upstream)
  const u16* qr0 = Qb + ((size_t)b * S_ + q0 + 32 * wv + lo) * D_ + h * 64;
  bf16x8 qa[2][2];
  qa[0][0] = *(const bf16x8*)(qr0 + 8 * hi);
  qa[0][1] = *(const bf16x8*)(qr0 + 32 + 8 * hi);
  qa[1][0] = *(const bf16x8*)(qr0 + (size_t)16 * D_ + 8 * hi);
  qa[1][1] = *(const bf16x8*)(qr0 + (size_t)16 * D_ + 32 + 8 * hi);

  auto stage8 = [&](unsigned char* dst, const char* srcbase, size_t rs) {
#pragma unroll
    for (int p = 0; p < 2; ++p) {
      int cid = p * 4 + wv;
      int slot = cid * 64 + lane;
      int r = slot >> 3, c = slot & 7;
      gld16(srcbase + (size_t)r * rs + ((c ^ (r & 7)) * 16), dst + cid * 1024);
    }
  };

  stage8(sK[0], kg, 2048);
  stage8(sV[0], vg, 4096);

  f32x4 acc[2][4];
#pragma unroll
  for (int hf = 0; hf < 2; ++hf)
#pragma unroll
    for (int i = 0; i < 4; ++i) acc[hf][i] = (f32x4){0.f, 0.f, 0.f, 0.f};
  float mrow[2] = {-3e38f, -3e38f}, lrow[2] = {0.f, 0.f};
  const unsigned long long* mrp = M1 + ((size_t)b * S_ + q0 + 32 * wv + lo) * NT_;

  for (int kt = 0; kt < NT_; ++kt) {
    int cur = kt & 1;
    if (kt < NT_ - 1) {
      stage8(sK[cur ^ 1], kg + (size_t)(kt + 1) * 64 * 2048, 2048);
      stage8(sV[cur ^ 1], vg + (size_t)(kt + 1) * 128, 4096);
      asm volatile("s_waitcnt vmcnt(4)" ::: "memory");
    } else {
      asm volatile("s_waitcnt vmcnt(0)" ::: "memory");
    }
    __builtin_amdgcn_s_barrier();
    __builtin_amdgcn_sched_barrier(0);

    unsigned long long mwh[2];
    mwh[0] = mrp[kt] >> (unsigned)(4 * hi);
    mwh[1] = mrp[(size_t)16 * NT_ + kt] >> (unsigned)(4 * hi);

    // QK^T swapped: sc[half][nf][reg] = S[key=16nf+4hi+reg][q]
    f32x4 sc[2][4];
    __builtin_amdgcn_s_setprio(1);
#pragma unroll
    for (int nf = 0; nf < 4; ++nf) {
      int key = 16 * nf + lo;
      bf16x8 kb0 = *(const bf16x8*)(sK[cur] + key * 128 + (((0 + hi) ^ (key & 7)) * 16));
      bf16x8 kb1 = *(const bf16x8*)(sK[cur] + key * 128 + (((4 + hi) ^ (key & 7)) * 16));
      f32x4 z0 = (f32x4){0.f, 0.f, 0.f, 0.f};
      f32x4 z1 = (f32x4){0.f, 0.f, 0.f, 0.f};
      z0 = __builtin_amdgcn_mfma_f32_16x16x32_bf16(kb0, qa[0][0], z0, 0, 0, 0);
      z1 = __builtin_amdgcn_mfma_f32_16x16x32_bf16(kb0, qa[1][0], z1, 0, 0, 0);
      z0 = __builtin_amdgcn_mfma_f32_16x16x32_bf16(kb1, qa[0][1], z0, 0, 0, 0);
      z1 = __builtin_amdgcn_mfma_f32_16x16x32_bf16(kb1, qa[1][1], z1, 0, 0, 0);
      sc[0][nf] = z0; sc[1][nf] = z1;
    }
    __builtin_amdgcn_s_setprio(0);

#pragma unroll
    for (int hf2 = 0; hf2 < 2; ++hf2) {
      unsigned long long mw = mwh[hf2];
      float t0 = fmaxf(fmaxf(sc[hf2][0][0], sc[hf2][0][1]), fmaxf(sc[hf2][0][2], sc[hf2][0][3]));
      float t1 = fmaxf(fmaxf(sc[hf2][1][0], sc[hf2][1][1]), fmaxf(sc[hf2][1][2], sc[hf2][1][3]));
      float t2 = fmaxf(fmaxf(sc[hf2][2][0], sc[hf2][2][1]), fmaxf(sc[hf2][2][2], sc[hf2][2][3]));
      float t3 = fmaxf(fmaxf(sc[hf2][3][0], sc[hf2][3][1]), fmaxf(sc[hf2][3][2], sc[hf2][3][3]));
      float tm = fmaxf(fmaxf(t0, t1), fmaxf(t2, t3));
      tm = fmaxf(tm, __shfl_xor(tm, 16));
      tm = fmaxf(tm, __shfl_xor(tm, 32));
      float mnew = fmaxf(mrow[hf2], tm);
      float fsc = __builtin_amdgcn_exp2f(mrow[hf2] - mnew);
      mrow[hf2] = mnew;

      unsigned nlo = ~(unsigned)mw;
      unsigned nhi = ~(unsigned)(mw >> 32);
      float p[4][4];
#pragma unroll
      for (int nf = 0; nf < 4; ++nf) {
        unsigned hfm = (nf < 2) ? nlo : nhi;
#pragma unroll
        for (int r = 0; r < 4; ++r) {
          float e = __builtin_amdgcn_exp2f(sc[hf2][nf][r] - mnew);
          int keep = ((int)(hfm << (31 - (16 * (nf & 1) + r)))) >> 31;
          p[nf][r] = __uint_as_float(__float_as_uint(e) & (unsigned)keep);
        }
      }
      float s0 = (p[0][0] + p[0][1]) + (p[0][2] + p[0][3]);
      float s1 = (p[1][0] + p[1][1]) + (p[1][2] + p[1][3]);
      float s2 = (p[2][0] + p[2][1]) + (p[2][2] + p[2][3]);
      float s3 = (p[3][0] + p[3][1]) + (p[3][2] + p[3][3]);
      float rs = (s0 + s1) + (s2 + s3);
      rs += __shfl_xor(rs, 16);
      rs += __shfl_xor(rs, 32);
      lrow[hf2] = lrow[hf2] * fsc + rs;
#pragma unroll
      for (int nd = 0; nd < 4; ++nd) acc[hf2][nd] *= fsc;

      int rq = 16 * hf2 + lo;
#pragma unroll
      for (int nf = 0; nf < 4; ++nf) {
        unsigned w0 = cvtpk(p[nf][0], p[nf][1]);
        unsigned w1 = cvtpk(p[nf][2], p[nf][3]);
        int dw = rq * 32 + ((8 * nf + 2 * hi) ^ ((lo & 7) << 2));
        *(uint2*)(sPw + dw) = make_uint2(w0, w1);
      }
    }

    // PV: acc[half][nd] (d=16nd+4hi+reg, q) += V^T chunk . P chunk
    __builtin_amdgcn_s_setprio(1);
#pragma unroll
    for (int mh = 0; mh < 2; ++mh) {
      bf16x8 pf0 = *(const bf16x8*)(sPw + (lo * 32 + ((16 * mh + 4 * hi) ^ ((lo & 7) << 2))));
      bf16x8 pf1 = *(const bf16x8*)(sPw + ((16 + lo) * 32 + ((16 * mh + 4 * hi) ^ ((lo & 7) << 2))));
#pragma unroll
      for (int nd = 0; nd < 4; ++nd) {
        int d = 16 * nd + lo;
        bf16x8 vb = *(const bf16x8*)(sV[cur] + d * 128 + (((4 * mh + hi) ^ (d & 7)) * 16));
        acc[0][nd] = __builtin_amdgcn_mfma_f32_16x16x32_bf16(vb, pf0, acc[0][nd], 0, 0, 0);
        acc[1][nd] = __builtin_amdgcn_mfma_f32_16x16x32_bf16(vb, pf1, acc[1][nd], 0, 0, 0);
      }
    }
    __builtin_amdgcn_s_setprio(0);

    __builtin_amdgcn_sched_barrier(0);
    __builtin_amdgcn_s_barrier();
  }

#pragma unroll
  for (int hf = 0; hf < 2; ++hf) {
    float inv = lrow[hf] > 0.f ? 1.f / lrow[hf] : 0.f;
    u16* crow = CTX + ((size_t)b * S_ + q0 + 32 * wv + 16 * hf + lo) * D_ + h * 64;
#pragma unroll
    for (int nd = 0; nd < 4; ++nd) {
      unsigned w0 = (unsigned)f2bf(acc[hf][nd][0] * inv) | ((unsigned)f2bf(acc[hf][nd][1] * inv) << 16);
      unsigned w1 = (unsigned)f2bf(acc[hf][nd][2] * inv) | ((unsigned)f2bf(acc[hf][nd][3] * inv) << 16);
      *(uint2*)(crow + 16 * nd + 4 * hi) = make_uint2(w0, w1);
    }
  }
}

// ---------------- launch ----------------
extern "C" void kernel_launch(void* const* d_in, const int* in_sizes, int n_in,
                              void* d_out, int out_size, void* d_ws, size_t ws_size,
                              hipStream_t stream) {
  const float* key   = (const float*)d_in[0];
  const float* value = (const float*)d_in[1];
  const float* query = (const float*)d_in[2];
  const void*  mask  = d_in[3];
  const float* Wq = (const float*)d_in[4];
  const float* bq = (const float*)d_in[5];
  const float* Wk = (const float*)d_in[6];
  const float* bk = (const float*)d_in[7];
  const float* Wv = (const float*)d_in[8];
  const float* bv = (const float*)d_in[9];
  const float* Wo = (const float*)d_in[10];
  const float* bo = (const float*)d_in[11];

  u16* Qb  = (u16*)d_ws;                 // Q proj (bf16), later ctx (safe alias)
  u16* Kb  = Qb + NE;
  u16* VTb = Kb + NE;                    // V stored [b][h][dn][s]
  u16* Xq  = VTb + NE;
  u16* Xk  = Xq + NE;
  u16* Xv  = Xk + NE;
  u16* WT  = Xv + NE;                    // 4 transposed bf16 weights
  unsigned long long* M1 = (unsigned long long*)(WT + 4 * DD);
  unsigned int* flags = (unsigned int*)(M1 + (size_t)B_ * S_ * NT_);

  hipMemsetAsync(flags, 0, 8, stream);
  detect_mask_fmt<<<128, 256, 0, stream>>>((const uint4*)mask, flags);
  prep_bits<<<512, 256, 0, stream>>>(mask, flags, M1);
  cvt_all<<<8192, 256, 0, stream>>>((const float4*)key, (const float4*)value, (const float4*)query,
                                    (bf16x8*)Xk, (bf16x8*)Xv, (bf16x8*)Xq,
                                    Wq, Wk, Wv, Wo, WT);

  const float QSCALE = 0.125f * 1.4426950408889634f;   // 1/sqrt(64) * log2(e)
  GArgs g3;
  g3.A[0] = Xq; g3.W[0] = WT + 0 * DD; g3.bias[0] = bq; g3.C[0] = Qb;  g3.scale[0] = QSCALE; g3.mode[0] = 0;
  g3.A[1] = Xk; g3.W[1] = WT + 1 * DD; g3.bias[1] = bk; g3.C[1] = Kb;  g3.scale[1] = 1.f;    g3.mode[1] = 0;
  g3.A[2] = Xv; g3.W[2] = WT + 2 * DD; g3.bias[2] = bv; g3.C[2] = VTb; g3.scale[2] = 1.f;    g3.mode[2] = 2;
  gemm_bf16<<<dim3(D_ / 128, (B_ * S_) / 128, 3), 256, 0, stream>>>(g3);

  attn_mfma2<<<dim3(S_ / 128, B_ * H_), 256, 0, stream>>>(Qb, Kb, VTb, M1, Qb);

  GArgs go;
  go.A[0] = Qb; go.W[0] = WT + 3 * DD; go.bias[0] = bo; go.C[0] = d_out; go.scale[0] = 1.f; go.mode[0] = 1;
  go.A[1] = Qb; go.W[1] = WT + 3 * DD; go.bias[1] = bo; go.C[1] = d_out; go.scale[1] = 1.f; go.mode[1] = 1;
  go.A[2] = Qb; go.W[2] = WT + 3 * DD; go.bias[2] = bo; go.C[2] = d_out; go.scale[2] = 1.f; go.mode[2] = 1;
  gemm_bf16<<<dim3(D_ / 128, (B_ * S_) / 128, 1), 256, 0, stream>>>(go);
}